// Round 1
// baseline (827.648 us; speedup 1.0000x reference)
//
#include <hip/hip_runtime.h>

#define NPIX 16384
#define CCH 256
#define INTR 128
#define REDD 32
#define NB 8
#define SLOPE 0.1f
#define BNEPS 1e-5f

// workspace offsets (floats)
#define OFF_GX    0            // 8*256*256 = 524288
#define OFF_YM    524288       // 2048
#define OFF_SC    526336       // 2048
#define OFF_RS    528384       // 2048
#define OFF_QS    530432       // 1024
#define OFF_VS    531456       // 1024
#define OFF_SWG   532480       // 128
#define OFF_TWG   532608       // 128
#define OFF_SOUT  532736       // 256
#define OFF_TOUT  532992       // 256
#define OFF_T1    533248       // 8*128*256 = 262144
#define OFF_M     795392       // 8*128*128 = 131072
#define OFF_WAV   926464       // 262144
#define OFF_W2    1188608      // 262144
#define OFF_W7    1450752      // 524288
#define OFF_B6    1975040      // 2048

// ---------- 1. per-(b,c) spatial mean ----------
__global__ __launch_bounds__(256) void mean_kernel(const float* __restrict__ x,
                                                   float* __restrict__ ym) {
    int row = blockIdx.x;  // b*256 + c
    const float4* p4 = (const float4*)(x + (size_t)row * NPIX);
    float s = 0.f;
    for (int i = threadIdx.x; i < NPIX / 4; i += 256) {
        float4 v = p4[i];
        s += (v.x + v.y) + (v.z + v.w);
    }
    for (int off = 32; off > 0; off >>= 1) s += __shfl_xor(s, off);
    __shared__ float red[4];
    if ((threadIdx.x & 63) == 0) red[threadIdx.x >> 6] = s;
    __syncthreads();
    if (threadIdx.x == 0)
        ym[row] = (red[0] + red[1] + red[2] + red[3]) * (1.f / NPIX);
}

// ---------- 2. SE block -> scale[b,c], rsum[b,c] = N*scale*mean ----------
__global__ __launch_bounds__(256) void se_kernel(const float* __restrict__ ym,
                                                 const float* __restrict__ se_w1,
                                                 const float* __restrict__ se_w2,
                                                 float* __restrict__ scale,
                                                 float* __restrict__ rsum) {
    int b = blockIdx.x, t = threadIdx.x;
    __shared__ float ys[CCH];
    __shared__ float y1s[REDD];
    ys[t] = ym[b * CCH + t];
    __syncthreads();
    if (t < REDD) {
        float a = 0.f;
        #pragma unroll 4
        for (int c = 0; c < CCH; ++c) a += se_w1[t * CCH + c] * ys[c];
        y1s[t] = a > 0.f ? a : SLOPE * a;
    }
    __syncthreads();
    float a = 0.f;
    #pragma unroll
    for (int r = 0; r < REDD; ++r) a += se_w2[t * REDD + r] * y1s[r];
    float sg = 1.f / (1.f + expf(-a));
    scale[b * CCH + t] = sg;
    rsum[b * CCH + t] = 16384.f * sg * ys[t];
}

// ---------- 3. BN constant folding ----------
__global__ __launch_bounds__(256) void prep_kernel(const float* __restrict__ g_wg, const float* __restrict__ be_wg,
                                                   const float* __restrict__ rm_wg, const float* __restrict__ rv_wg,
                                                   const float* __restrict__ g_out, const float* __restrict__ be_out,
                                                   const float* __restrict__ rm_out, const float* __restrict__ rv_out,
                                                   float* __restrict__ swg, float* __restrict__ twg,
                                                   float* __restrict__ sout, float* __restrict__ tout) {
    int t = threadIdx.x;
    if (t < INTR) {
        float s = g_wg[t] / sqrtf(rv_wg[t] + BNEPS);
        swg[t] = s;
        twg[t] = be_wg[t] - rm_wg[t] * s;
    }
    float s = g_out[t] / sqrtf(rv_out[t] + BNEPS);
    sout[t] = s;
    tout[t] = be_out[t] - rm_out[t] * s;
}

// ---------- 4. qs[b,i]=Wq.rsum, vs[b,j]=Wv.rsum ----------
__global__ __launch_bounds__(256) void qsvs_kernel(const float* __restrict__ wq,
                                                   const float* __restrict__ wv,
                                                   const float* __restrict__ rsum,
                                                   float* __restrict__ qs, float* __restrict__ vs) {
    int b = blockIdx.x, t = threadIdx.x;
    __shared__ float rs[CCH];
    rs[t] = rsum[b * CCH + t];
    __syncthreads();
    const float* w = (t < INTR) ? (wq + t * CCH) : (wv + (t - INTR) * CCH);
    float a = 0.f;
    #pragma unroll 4
    for (int c = 0; c < CCH; ++c) a += w[c] * rs[c];
    if (t < INTR) qs[b * INTR + t] = a;
    else          vs[b * INTR + (t - INTR)] = a;
}

// ---------- 5. Gram: Gx[b,c,c'] = sum_n x[b,c,n]*x[b,c',n] (split-K atomics) ----------
__global__ __launch_bounds__(256) void gram_kernel(const float* __restrict__ x,
                                                   float* __restrict__ Gx) {
    int bid = blockIdx.x;
    int tile = bid & 3;
    int chunk = (bid >> 2) & 31;   // 32 chunks of 512
    int b = bid >> 7;
    int rowbase = (tile >> 1) * 128;
    int colbase = (tile & 1) * 128;
    int n0 = chunk * 512;
    __shared__ float As[32][129];
    __shared__ float Bs[32][129];
    int tid = threadIdx.x;
    int tx = tid & 15, ty = tid >> 4;
    float acc[8][8] = {};
    const float* xb = x + (size_t)b * CCH * NPIX;
    for (int k0 = 0; k0 < 512; k0 += 32) {
        #pragma unroll
        for (int e = 0; e < 16; ++e) {
            int lin = tid + 256 * e;         // 0..4095
            int r = lin >> 5, k = lin & 31;
            As[k][r] = xb[(size_t)(rowbase + r) * NPIX + n0 + k0 + k];
            Bs[k][r] = xb[(size_t)(colbase + r) * NPIX + n0 + k0 + k];
        }
        __syncthreads();
        for (int k = 0; k < 32; ++k) {
            float a[8], bb[8];
            #pragma unroll
            for (int ii = 0; ii < 8; ++ii) a[ii] = As[k][ty + 16 * ii];
            #pragma unroll
            for (int jj = 0; jj < 8; ++jj) bb[jj] = Bs[k][tx + 16 * jj];
            #pragma unroll
            for (int ii = 0; ii < 8; ++ii)
                #pragma unroll
                for (int jj = 0; jj < 8; ++jj)
                    acc[ii][jj] = fmaf(a[ii], bb[jj], acc[ii][jj]);
        }
        __syncthreads();
    }
    float* G = Gx + (size_t)b * CCH * CCH;
    #pragma unroll
    for (int ii = 0; ii < 8; ++ii)
        #pragma unroll
        for (int jj = 0; jj < 8; ++jj)
            atomicAdd(&G[(rowbase + ty + 16 * ii) * CCH + colbase + tx + 16 * jj], acc[ii][jj]);
}

// ---------- 6. T1[b,i,c'] = (sum_c wq[i,c]*s_c*Gx[c,c'])*s_c' ----------
__global__ __launch_bounds__(256) void t1_kernel(const float* __restrict__ wq,
                                                 const float* __restrict__ scale,
                                                 const float* __restrict__ Gx,
                                                 float* __restrict__ T1) {
    int bid = blockIdx.x;
    int i = bid & 127, b = bid >> 7;
    int t = threadIdx.x;
    __shared__ float sw[CCH];
    sw[t] = wq[i * CCH + t] * scale[b * CCH + t];
    __syncthreads();
    const float* G = Gx + (size_t)b * CCH * CCH;
    float acc = 0.f;
    #pragma unroll 4
    for (int c = 0; c < CCH; ++c) acc += sw[c] * G[c * CCH + t];
    T1[(size_t)b * INTR * CCH + i * CCH + t] = acc * scale[b * CCH + t];
}

// ---------- 7. S row + softmax -> M[b,j,i] = att[b,i,j] ----------
__global__ __launch_bounds__(128) void ssoft_kernel(const float* __restrict__ T1,
                                                    const float* __restrict__ wv,
                                                    const float* __restrict__ bq,
                                                    const float* __restrict__ bv,
                                                    const float* __restrict__ qs,
                                                    const float* __restrict__ vs,
                                                    float* __restrict__ M) {
    int bid = blockIdx.x;
    int i = bid & 127, b = bid >> 7;
    int j = threadIdx.x;  // 0..127
    __shared__ float t1s[CCH];
    __shared__ float redm[2], reds[2];
    t1s[j] = T1[(size_t)b * INTR * CCH + i * CCH + j];
    t1s[j + 128] = T1[(size_t)b * INTR * CCH + i * CCH + j + 128];
    __syncthreads();
    const float* wvr = wv + j * CCH;
    float acc = 0.f;
    #pragma unroll 4
    for (int c = 0; c < CCH; ++c) acc += t1s[c] * wvr[c];
    acc += bq[i] * vs[b * INTR + j] + bv[j] * qs[b * INTR + i] + 16384.f * bq[i] * bv[j];
    // softmax over j (128 threads = 2 waves)
    float m = acc;
    for (int off = 32; off > 0; off >>= 1) m = fmaxf(m, __shfl_xor(m, off));
    int w = j >> 6;
    if ((j & 63) == 0) redm[w] = m;
    __syncthreads();
    m = fmaxf(redm[0], redm[1]);
    float e = expf(acc - m);
    float s = e;
    for (int off = 32; off > 0; off >>= 1) s += __shfl_xor(s, off);
    if ((j & 63) == 0) reds[w] = s;
    __syncthreads();
    s = reds[0] + reds[1];
    M[(size_t)b * INTR * INTR + j * INTR + i] = e / s;   // transposed store
}

// ---------- 8. Wav[b,i,c] = sum_j M[b,i,j]*wk[j,c] ----------
__global__ __launch_bounds__(256) void wav_kernel(const float* __restrict__ M,
                                                  const float* __restrict__ wk,
                                                  float* __restrict__ Wav) {
    int bid = blockIdx.x;
    int i = bid & 127, b = bid >> 7;
    int t = threadIdx.x;
    __shared__ float ms[INTR];
    if (t < INTR) ms[t] = M[(size_t)b * INTR * INTR + i * INTR + t];
    __syncthreads();
    float acc = 0.f;
    #pragma unroll 4
    for (int jj = 0; jj < INTR; ++jj) acc += ms[jj] * wk[jj * CCH + t];
    Wav[(size_t)b * INTR * CCH + i * CCH + t] = acc;
}

// ---------- 9. bias chain -> b6[b,c] ----------
__global__ __launch_bounds__(256) void biaschain_kernel(const float* __restrict__ M,
                                                        const float* __restrict__ bk,
                                                        const float* __restrict__ wwg,
                                                        const float* __restrict__ swg,
                                                        const float* __restrict__ twg,
                                                        const float* __restrict__ wout,
                                                        const float* __restrict__ bout,
                                                        const float* __restrict__ sout,
                                                        const float* __restrict__ tout,
                                                        float* __restrict__ b6) {
    int b = blockIdx.x, t = threadIdx.x;
    __shared__ float bavs[INTR], b2s[INTR];
    if (t < INTR) {
        float a = 0.f;
        #pragma unroll 4
        for (int j = 0; j < INTR; ++j) a += M[(size_t)b * INTR * INTR + t * INTR + j] * bk[j];
        bavs[t] = a;
    }
    __syncthreads();
    if (t < INTR) {
        float a = 0.f;
        #pragma unroll 4
        for (int i = 0; i < INTR; ++i) a += wwg[t * INTR + i] * bavs[i];
        b2s[t] = swg[t] * a + twg[t];
    }
    __syncthreads();
    float a = 0.f;
    #pragma unroll 4
    for (int o = 0; o < INTR; ++o) a += wout[t * INTR + o] * b2s[o];
    float b5 = a + bout[t];
    b6[b * CCH + t] = sout[t] * b5 + tout[t];
}

// ---------- 10. W2[b,o,c] = swg[o]*sum_i wwg[o,i]*Wav[b,i,c] ----------
__global__ __launch_bounds__(256) void w2_kernel(const float* __restrict__ wwg,
                                                 const float* __restrict__ Wav,
                                                 const float* __restrict__ swg,
                                                 float* __restrict__ W2) {
    int bid = blockIdx.x;
    int o = bid & 127, b = bid >> 7;
    int t = threadIdx.x;
    __shared__ float wr[INTR];
    if (t < INTR) wr[t] = wwg[o * INTR + t];
    __syncthreads();
    float acc = 0.f;
    #pragma unroll 4
    for (int i = 0; i < INTR; ++i) acc += wr[i] * Wav[(size_t)b * INTR * CCH + i * CCH + t];
    W2[(size_t)b * INTR * CCH + o * CCH + t] = swg[o] * acc;
}

// ---------- 11. W7[b,c,c'] = (sout[c]*sum_o wout[c,o]*W2[b,o,c'] + I)*scale[b,c'] ----------
__global__ __launch_bounds__(256) void w7_kernel(const float* __restrict__ wout,
                                                 const float* __restrict__ W2,
                                                 const float* __restrict__ sout,
                                                 const float* __restrict__ scale,
                                                 float* __restrict__ W7) {
    int bid = blockIdx.x;
    int c = bid & 255, b = bid >> 8;
    int t = threadIdx.x;
    __shared__ float wr[INTR];
    if (t < INTR) wr[t] = wout[c * INTR + t];
    __syncthreads();
    float acc = 0.f;
    #pragma unroll 4
    for (int o = 0; o < INTR; ++o) acc += wr[o] * W2[(size_t)b * INTR * CCH + o * CCH + t];
    float w6 = sout[c] * acc + ((c == t) ? 1.f : 0.f);
    W7[(size_t)b * CCH * CCH + c * CCH + t] = w6 * scale[b * CCH + t];
}

// ---------- 12. out = leaky(W7 @ x + b6) ----------
__global__ __launch_bounds__(256) void final_kernel(const float* __restrict__ W7,
                                                    const float* __restrict__ x,
                                                    const float* __restrict__ b6,
                                                    float* __restrict__ out) {
    int bid = blockIdx.x;
    int ntile = bid & 127;
    int mtile = (bid >> 7) & 1;
    int b = bid >> 8;
    int rowbase = mtile * 128;
    int n0 = ntile * 128;
    __shared__ float Ws[32][129];
    __shared__ float Xs[32][129];
    int tid = threadIdx.x;
    int tx = tid & 15, ty = tid >> 4;
    float acc[8][8] = {};
    const float* Wb = W7 + (size_t)b * CCH * CCH;
    const float* xb = x + (size_t)b * CCH * NPIX;
    for (int k0 = 0; k0 < CCH; k0 += 32) {
        #pragma unroll
        for (int e = 0; e < 16; ++e) {
            int lin = tid + 256 * e;          // 0..4095
            int r = lin >> 5, k = lin & 31;
            Ws[k][r] = Wb[(rowbase + r) * CCH + k0 + k];
            int cc = lin & 127, kk = lin >> 7;
            Xs[kk][cc] = xb[(size_t)(k0 + kk) * NPIX + n0 + cc];
        }
        __syncthreads();
        for (int k = 0; k < 32; ++k) {
            float a[8], bb[8];
            #pragma unroll
            for (int ii = 0; ii < 8; ++ii) a[ii] = Ws[k][ty + 16 * ii];
            #pragma unroll
            for (int jj = 0; jj < 8; ++jj) bb[jj] = Xs[k][tx + 16 * jj];
            #pragma unroll
            for (int ii = 0; ii < 8; ++ii)
                #pragma unroll
                for (int jj = 0; jj < 8; ++jj)
                    acc[ii][jj] = fmaf(a[ii], bb[jj], acc[ii][jj]);
        }
        __syncthreads();
    }
    #pragma unroll
    for (int ii = 0; ii < 8; ++ii) {
        int c = rowbase + ty + 16 * ii;
        float bias = b6[b * CCH + c];
        float* op = out + (size_t)b * CCH * NPIX + (size_t)c * NPIX + n0;
        #pragma unroll
        for (int jj = 0; jj < 8; ++jj) {
            float v = acc[ii][jj] + bias;
            op[tx + 16 * jj] = v > 0.f ? v : SLOPE * v;
        }
    }
}

extern "C" void kernel_launch(void* const* d_in, const int* in_sizes, int n_in,
                              void* d_out, int out_size, void* d_ws, size_t ws_size,
                              hipStream_t stream) {
    (void)in_sizes; (void)n_in; (void)out_size; (void)ws_size;
    const float* x      = (const float*)d_in[0];
    const float* se_w1  = (const float*)d_in[1];
    const float* se_w2  = (const float*)d_in[2];
    const float* wq     = (const float*)d_in[3];
    const float* bq     = (const float*)d_in[4];
    const float* wk     = (const float*)d_in[5];
    const float* bk     = (const float*)d_in[6];
    const float* wv     = (const float*)d_in[7];
    const float* bv     = (const float*)d_in[8];
    const float* w_wg   = (const float*)d_in[9];
    const float* g_wg   = (const float*)d_in[10];
    const float* be_wg  = (const float*)d_in[11];
    const float* rm_wg  = (const float*)d_in[12];
    const float* rv_wg  = (const float*)d_in[13];
    const float* w_out  = (const float*)d_in[14];
    const float* b_out  = (const float*)d_in[15];
    const float* g_out  = (const float*)d_in[16];
    const float* be_out = (const float*)d_in[17];
    const float* rm_out = (const float*)d_in[18];
    const float* rv_out = (const float*)d_in[19];
    float* out = (float*)d_out;
    float* ws = (float*)d_ws;

    hipMemsetAsync(ws + OFF_GX, 0, (size_t)NB * CCH * CCH * sizeof(float), stream);
    mean_kernel<<<NB * CCH, 256, 0, stream>>>(x, ws + OFF_YM);
    se_kernel<<<NB, 256, 0, stream>>>(ws + OFF_YM, se_w1, se_w2, ws + OFF_SC, ws + OFF_RS);
    prep_kernel<<<1, 256, 0, stream>>>(g_wg, be_wg, rm_wg, rv_wg, g_out, be_out, rm_out, rv_out,
                                       ws + OFF_SWG, ws + OFF_TWG, ws + OFF_SOUT, ws + OFF_TOUT);
    qsvs_kernel<<<NB, 256, 0, stream>>>(wq, wv, ws + OFF_RS, ws + OFF_QS, ws + OFF_VS);
    gram_kernel<<<NB * 32 * 4, 256, 0, stream>>>(x, ws + OFF_GX);
    t1_kernel<<<NB * INTR, 256, 0, stream>>>(wq, ws + OFF_SC, ws + OFF_GX, ws + OFF_T1);
    ssoft_kernel<<<NB * INTR, 128, 0, stream>>>(ws + OFF_T1, wv, bq, bv, ws + OFF_QS, ws + OFF_VS, ws + OFF_M);
    wav_kernel<<<NB * INTR, 256, 0, stream>>>(ws + OFF_M, wk, ws + OFF_WAV);
    biaschain_kernel<<<NB, 256, 0, stream>>>(ws + OFF_M, bk, w_wg, ws + OFF_SWG, ws + OFF_TWG,
                                             w_out, b_out, ws + OFF_SOUT, ws + OFF_TOUT, ws + OFF_B6);
    w2_kernel<<<NB * INTR, 256, 0, stream>>>(w_wg, ws + OFF_WAV, ws + OFF_SWG, ws + OFF_W2);
    w7_kernel<<<NB * CCH, 256, 0, stream>>>(w_out, ws + OFF_W2, ws + OFF_SOUT, ws + OFF_SC, ws + OFF_W7);
    final_kernel<<<NB * 2 * 128, 256, 0, stream>>>(ws + OFF_W7, x, ws + OFF_B6, out);
}

// Round 2
// 383.239 us; speedup vs baseline: 2.1596x; 2.1596x over previous
//
#include <hip/hip_runtime.h>

#define NPIX 16384
#define CCH 256
#define INTR 128
#define REDD 32
#define NB 8
#define SLOPE 0.1f
#define BNEPS 1e-5f

typedef __attribute__((ext_vector_type(8))) short bf16x8;
typedef __attribute__((ext_vector_type(16))) float f32x16;

// workspace offsets (floats)
#define OFF_GX    0            // 8*256*256 = 524288
#define OFF_YM    524288       // 2048
#define OFF_SC    526336       // 2048
#define OFF_RS    528384       // 2048
#define OFF_QS    530432       // 1024
#define OFF_VS    531456       // 1024
#define OFF_SWG   532480       // 128
#define OFF_TWG   532608       // 128
#define OFF_SOUT  532736       // 256
#define OFF_TOUT  532992       // 256
#define OFF_T1    533248       // 8*128*256 = 262144
#define OFF_M     795392       // 8*128*128 = 131072
#define OFF_WAV   926464       // 262144
#define OFF_W2    1188608      // 262144
#define OFF_W7    1450752      // used as ushort[8*256*256] = 1 MB (fits old 2 MB slot)
#define OFF_B6    1975040      // 2048

__device__ __forceinline__ unsigned short bf1(float f) {
    unsigned int u = __float_as_uint(f);
    return (unsigned short)((u + 0x7fffu + ((u >> 16) & 1u)) >> 16);
}

__device__ __forceinline__ void cvt8(const float4 a, const float4 c, uint4& hp, uint4& lp) {
    float f[8] = {a.x, a.y, a.z, a.w, c.x, c.y, c.z, c.w};
    unsigned int h[8], lo[8];
    #pragma unroll
    for (int i = 0; i < 8; ++i) {
        unsigned int u = __float_as_uint(f[i]);
        h[i] = (u + 0x7fffu + ((u >> 16) & 1u)) >> 16;
        float hf = __uint_as_float(h[i] << 16);
        float d = f[i] - hf;
        unsigned int ud = __float_as_uint(d);
        lo[i] = (ud + 0x7fffu + ((ud >> 16) & 1u)) >> 16;
    }
    hp = make_uint4(h[0] | (h[1] << 16), h[2] | (h[3] << 16), h[4] | (h[5] << 16), h[6] | (h[7] << 16));
    lp = make_uint4(lo[0] | (lo[1] << 16), lo[2] | (lo[3] << 16), lo[4] | (lo[5] << 16), lo[6] | (lo[7] << 16));
}

// ---------- 1. per-(b,c) spatial mean ----------
__global__ __launch_bounds__(256) void mean_kernel(const float* __restrict__ x,
                                                   float* __restrict__ ym) {
    int row = blockIdx.x;  // b*256 + c
    const float4* p4 = (const float4*)(x + (size_t)row * NPIX);
    float s = 0.f;
    for (int i = threadIdx.x; i < NPIX / 4; i += 256) {
        float4 v = p4[i];
        s += (v.x + v.y) + (v.z + v.w);
    }
    for (int off = 32; off > 0; off >>= 1) s += __shfl_xor(s, off);
    __shared__ float red[4];
    if ((threadIdx.x & 63) == 0) red[threadIdx.x >> 6] = s;
    __syncthreads();
    if (threadIdx.x == 0)
        ym[row] = (red[0] + red[1] + red[2] + red[3]) * (1.f / NPIX);
}

// ---------- 2. SE block -> scale[b,c], rsum[b,c] = N*scale*mean ----------
__global__ __launch_bounds__(256) void se_kernel(const float* __restrict__ ym,
                                                 const float* __restrict__ se_w1,
                                                 const float* __restrict__ se_w2,
                                                 float* __restrict__ scale,
                                                 float* __restrict__ rsum) {
    int b = blockIdx.x, t = threadIdx.x;
    __shared__ float ys[CCH];
    __shared__ float y1s[REDD];
    ys[t] = ym[b * CCH + t];
    __syncthreads();
    if (t < REDD) {
        float a = 0.f;
        #pragma unroll 4
        for (int c = 0; c < CCH; ++c) a += se_w1[t * CCH + c] * ys[c];
        y1s[t] = a > 0.f ? a : SLOPE * a;
    }
    __syncthreads();
    float a = 0.f;
    #pragma unroll
    for (int r = 0; r < REDD; ++r) a += se_w2[t * REDD + r] * y1s[r];
    float sg = 1.f / (1.f + expf(-a));
    scale[b * CCH + t] = sg;
    rsum[b * CCH + t] = 16384.f * sg * ys[t];
}

// ---------- 3. BN constant folding ----------
__global__ __launch_bounds__(256) void prep_kernel(const float* __restrict__ g_wg, const float* __restrict__ be_wg,
                                                   const float* __restrict__ rm_wg, const float* __restrict__ rv_wg,
                                                   const float* __restrict__ g_out, const float* __restrict__ be_out,
                                                   const float* __restrict__ rm_out, const float* __restrict__ rv_out,
                                                   float* __restrict__ swg, float* __restrict__ twg,
                                                   float* __restrict__ sout, float* __restrict__ tout) {
    int t = threadIdx.x;
    if (t < INTR) {
        float s = g_wg[t] / sqrtf(rv_wg[t] + BNEPS);
        swg[t] = s;
        twg[t] = be_wg[t] - rm_wg[t] * s;
    }
    float s = g_out[t] / sqrtf(rv_out[t] + BNEPS);
    sout[t] = s;
    tout[t] = be_out[t] - rm_out[t] * s;
}

// ---------- 4. qs[b,i]=Wq.rsum, vs[b,j]=Wv.rsum ----------
__global__ __launch_bounds__(256) void qsvs_kernel(const float* __restrict__ wq,
                                                   const float* __restrict__ wv,
                                                   const float* __restrict__ rsum,
                                                   float* __restrict__ qs, float* __restrict__ vs) {
    int b = blockIdx.x, t = threadIdx.x;
    __shared__ float rs[CCH];
    rs[t] = rsum[b * CCH + t];
    __syncthreads();
    const float* w = (t < INTR) ? (wq + t * CCH) : (wv + (t - INTR) * CCH);
    float a = 0.f;
    #pragma unroll 4
    for (int c = 0; c < CCH; ++c) a += w[c] * rs[c];
    if (t < INTR) qs[b * INTR + t] = a;
    else          vs[b * INTR + (t - INTR)] = a;
}

// ---------- 5. Gram via MFMA, bf16 hi/lo split, 3 tiles (symmetry) ----------
// G[b] = H H^T + H L^T + L H^T  (L L^T negligible ~2^-18)
__global__ __launch_bounds__(256, 2) void gram_mfma_kernel(const float* __restrict__ x,
                                                           float* __restrict__ Gx) {
    __shared__ __align__(16) unsigned short Ah[128 * 64];
    __shared__ __align__(16) unsigned short Al[128 * 64];
    __shared__ __align__(16) unsigned short Bh[128 * 64];
    __shared__ __align__(16) unsigned short Bl[128 * 64];
    int bid = blockIdx.x;
    int chunk = bid & 31;            // 32 chunks of 512 pixels
    int t2 = bid >> 5;
    int tile = t2 % 3;               // 0:(0,0) 1:(128,128) 2:(0,128)+mirror
    int b = t2 / 3;
    int rowbase = (tile == 1) ? 128 : 0;
    int colbase = (tile == 0) ? 0 : 128;
    bool diag = (tile < 2);
    const float* xb = x + (size_t)b * CCH * NPIX;
    int n0 = chunk * 512;
    int tid = threadIdx.x;
    int l = tid & 63, w = tid >> 6;
    int wrow = (w >> 1) * 64, wcol = (w & 1) * 64;

    f32x16 accHH[2][2], accX[2][2];
    #pragma unroll
    for (int i = 0; i < 2; ++i)
        #pragma unroll
        for (int j = 0; j < 2; ++j)
            #pragma unroll
            for (int r = 0; r < 16; ++r) { accHH[i][j][r] = 0.f; accX[i][j][r] = 0.f; }

    for (int step = 0; step < 8; ++step) {
        int k0 = n0 + step * 64;
        __syncthreads();
        // stage + convert: panel 128 rows x 64 k, 1024 slots (row, seg of 8)
        #pragma unroll
        for (int e = 0; e < 4; ++e) {
            int slot = tid + 256 * e;
            int r = slot >> 3, sg = slot & 7;
            const float* src = &xb[(size_t)(rowbase + r) * NPIX + k0 + sg * 8];
            float4 v0 = *(const float4*)src;
            float4 v1 = *(const float4*)(src + 4);
            uint4 hp, lp;
            cvt8(v0, v1, hp, lp);
            int dst = r * 64 + ((sg ^ (r & 7)) << 3);
            *(uint4*)&Ah[dst] = hp;
            *(uint4*)&Al[dst] = lp;
            if (!diag) {
                const float* srcб = &xb[(size_t)(colbase + r) * NPIX + k0 + sg * 8];
                float4 u0 = *(const float4*)srcб;
                float4 u1 = *(const float4*)(srcб + 4);
                cvt8(u0, u1, hp, lp);
                *(uint4*)&Bh[dst] = hp;
                *(uint4*)&Bl[dst] = lp;
            }
        }
        __syncthreads();
        const unsigned short* BhP = diag ? Ah : Bh;
        const unsigned short* BlP = diag ? Al : Bl;
        #pragma unroll
        for (int kk = 0; kk < 4; ++kk) {
            bf16x8 ah[2], al2[2], bh[2], bl2[2];
            int useg = kk * 2 + (l >> 5);
            #pragma unroll
            for (int at = 0; at < 2; ++at) {
                int r = wrow + at * 32 + (l & 31);
                int off = r * 64 + ((useg ^ (r & 7)) << 3);
                ah[at] = *(const bf16x8*)&Ah[off];
                al2[at] = *(const bf16x8*)&Al[off];
            }
            #pragma unroll
            for (int bt = 0; bt < 2; ++bt) {
                int c = wcol + bt * 32 + (l & 31);
                int off = c * 64 + ((useg ^ (c & 7)) << 3);
                bh[bt] = *(const bf16x8*)&BhP[off];
                bl2[bt] = *(const bf16x8*)&BlP[off];
            }
            #pragma unroll
            for (int at = 0; at < 2; ++at)
                #pragma unroll
                for (int bt = 0; bt < 2; ++bt) {
                    accHH[at][bt] = __builtin_amdgcn_mfma_f32_32x32x16_bf16(ah[at], bh[bt], accHH[at][bt], 0, 0, 0);
                    accX[at][bt]  = __builtin_amdgcn_mfma_f32_32x32x16_bf16(ah[at], bl2[bt], accX[at][bt], 0, 0, 0);
                    accX[at][bt]  = __builtin_amdgcn_mfma_f32_32x32x16_bf16(al2[at], bh[bt], accX[at][bt], 0, 0, 0);
                }
        }
    }
    float* G = Gx + (size_t)b * CCH * CCH;
    #pragma unroll
    for (int at = 0; at < 2; ++at)
        #pragma unroll
        for (int bt = 0; bt < 2; ++bt)
            #pragma unroll
            for (int r = 0; r < 16; ++r) {
                int gr = rowbase + wrow + at * 32 + (r & 3) + ((r >> 2) << 3) + ((l >> 5) << 2);
                int gc = colbase + wcol + bt * 32 + (l & 31);
                float v = accHH[at][bt][r] + accX[at][bt][r];
                atomicAdd(&G[gr * CCH + gc], v);
                if (tile == 2) atomicAdd(&G[gc * CCH + gr], v);
            }
}

// ---------- 6. T1[b,i,c'] = (sum_c wq[i,c]*s_c*Gx[c,c'])*s_c' ----------
__global__ __launch_bounds__(256) void t1_kernel(const float* __restrict__ wq,
                                                 const float* __restrict__ scale,
                                                 const float* __restrict__ Gx,
                                                 float* __restrict__ T1) {
    int bid = blockIdx.x;
    int i = bid & 127, b = bid >> 7;
    int t = threadIdx.x;
    __shared__ float sw[CCH];
    sw[t] = wq[i * CCH + t] * scale[b * CCH + t];
    __syncthreads();
    const float* G = Gx + (size_t)b * CCH * CCH;
    float acc = 0.f;
    #pragma unroll 4
    for (int c = 0; c < CCH; ++c) acc += sw[c] * G[c * CCH + t];
    T1[(size_t)b * INTR * CCH + i * CCH + t] = acc * scale[b * CCH + t];
}

// ---------- 7. S row + softmax -> M[b,j,i] = att[b,i,j] ----------
__global__ __launch_bounds__(128) void ssoft_kernel(const float* __restrict__ T1,
                                                    const float* __restrict__ wv,
                                                    const float* __restrict__ bq,
                                                    const float* __restrict__ bv,
                                                    const float* __restrict__ qs,
                                                    const float* __restrict__ vs,
                                                    float* __restrict__ M) {
    int bid = blockIdx.x;
    int i = bid & 127, b = bid >> 7;
    int j = threadIdx.x;  // 0..127
    __shared__ float t1s[CCH];
    __shared__ float redm[2], reds[2];
    t1s[j] = T1[(size_t)b * INTR * CCH + i * CCH + j];
    t1s[j + 128] = T1[(size_t)b * INTR * CCH + i * CCH + j + 128];
    __syncthreads();
    const float* wvr = wv + j * CCH;
    float acc = 0.f;
    #pragma unroll 4
    for (int c = 0; c < CCH; ++c) acc += t1s[c] * wvr[c];
    acc += bq[i] * vs[b * INTR + j] + bv[j] * qs[b * INTR + i] + 16384.f * bq[i] * bv[j];
    float m = acc;
    for (int off = 32; off > 0; off >>= 1) m = fmaxf(m, __shfl_xor(m, off));
    int w = j >> 6;
    if ((j & 63) == 0) redm[w] = m;
    __syncthreads();
    m = fmaxf(redm[0], redm[1]);
    float e = expf(acc - m);
    float s = e;
    for (int off = 32; off > 0; off >>= 1) s += __shfl_xor(s, off);
    if ((j & 63) == 0) reds[w] = s;
    __syncthreads();
    s = reds[0] + reds[1];
    M[(size_t)b * INTR * INTR + j * INTR + i] = e / s;   // transposed store
}

// ---------- 8. Wav[b,i,c] = sum_j M[b,i,j]*wk[j,c] ----------
__global__ __launch_bounds__(256) void wav_kernel(const float* __restrict__ M,
                                                  const float* __restrict__ wk,
                                                  float* __restrict__ Wav) {
    int bid = blockIdx.x;
    int i = bid & 127, b = bid >> 7;
    int t = threadIdx.x;
    __shared__ float ms[INTR];
    if (t < INTR) ms[t] = M[(size_t)b * INTR * INTR + i * INTR + t];
    __syncthreads();
    float acc = 0.f;
    #pragma unroll 4
    for (int jj = 0; jj < INTR; ++jj) acc += ms[jj] * wk[jj * CCH + t];
    Wav[(size_t)b * INTR * CCH + i * CCH + t] = acc;
}

// ---------- 9. bias chain -> b6[b,c] ----------
__global__ __launch_bounds__(256) void biaschain_kernel(const float* __restrict__ M,
                                                        const float* __restrict__ bk,
                                                        const float* __restrict__ wwg,
                                                        const float* __restrict__ swg,
                                                        const float* __restrict__ twg,
                                                        const float* __restrict__ wout,
                                                        const float* __restrict__ bout,
                                                        const float* __restrict__ sout,
                                                        const float* __restrict__ tout,
                                                        float* __restrict__ b6) {
    int b = blockIdx.x, t = threadIdx.x;
    __shared__ float bavs[INTR], b2s[INTR];
    if (t < INTR) {
        float a = 0.f;
        #pragma unroll 4
        for (int j = 0; j < INTR; ++j) a += M[(size_t)b * INTR * INTR + t * INTR + j] * bk[j];
        bavs[t] = a;
    }
    __syncthreads();
    if (t < INTR) {
        float a = 0.f;
        #pragma unroll 4
        for (int i = 0; i < INTR; ++i) a += wwg[t * INTR + i] * bavs[i];
        b2s[t] = swg[t] * a + twg[t];
    }
    __syncthreads();
    float a = 0.f;
    #pragma unroll 4
    for (int o = 0; o < INTR; ++o) a += wout[t * INTR + o] * b2s[o];
    float b5 = a + bout[t];
    b6[b * CCH + t] = sout[t] * b5 + tout[t];
}

// ---------- 10. W2[b,o,c] = swg[o]*sum_i wwg[o,i]*Wav[b,i,c] ----------
__global__ __launch_bounds__(256) void w2_kernel(const float* __restrict__ wwg,
                                                 const float* __restrict__ Wav,
                                                 const float* __restrict__ swg,
                                                 float* __restrict__ W2) {
    int bid = blockIdx.x;
    int o = bid & 127, b = bid >> 7;
    int t = threadIdx.x;
    __shared__ float wr[INTR];
    if (t < INTR) wr[t] = wwg[o * INTR + t];
    __syncthreads();
    float acc = 0.f;
    #pragma unroll 4
    for (int i = 0; i < INTR; ++i) acc += wr[i] * Wav[(size_t)b * INTR * CCH + i * CCH + t];
    W2[(size_t)b * INTR * CCH + o * CCH + t] = swg[o] * acc;
}

// ---------- 11. W7bf16[b,c,c'] = bf16((sout[c]*sum_o wout[c,o]*W2[b,o,c'] + I)*scale[b,c']) ----------
__global__ __launch_bounds__(256) void w7_kernel(const float* __restrict__ wout,
                                                 const float* __restrict__ W2,
                                                 const float* __restrict__ sout,
                                                 const float* __restrict__ scale,
                                                 unsigned short* __restrict__ W7b) {
    int bid = blockIdx.x;
    int c = bid & 255, b = bid >> 8;
    int t = threadIdx.x;
    __shared__ float wr[INTR];
    if (t < INTR) wr[t] = wout[c * INTR + t];
    __syncthreads();
    float acc = 0.f;
    #pragma unroll 4
    for (int o = 0; o < INTR; ++o) acc += wr[o] * W2[(size_t)b * INTR * CCH + o * CCH + t];
    float w6 = sout[c] * acc + ((c == t) ? 1.f : 0.f);
    W7b[(size_t)b * CCH * CCH + c * CCH + t] = bf1(w6 * scale[b * CCH + t]);
}

// ---------- 12. out = leaky(W7 @ x + b6) via MFMA bf16 ----------
__global__ __launch_bounds__(256, 2) void final_mfma_kernel(const unsigned short* __restrict__ W7b,
                                                            const float* __restrict__ x,
                                                            const float* __restrict__ b6,
                                                            float* __restrict__ out) {
    __shared__ __align__(16) unsigned short Ws[128 * 64];
    __shared__ __align__(16) unsigned short Xs[128 * 64];
    int bid = blockIdx.x;
    int ct = bid & 1;
    int nt = (bid >> 1) & 127;
    int b = bid >> 8;
    int cbase = ct * 128, n0 = nt * 128;
    const float* xb = x + (size_t)b * CCH * NPIX;
    const unsigned short* Wb = W7b + (size_t)b * CCH * CCH;
    int tid = threadIdx.x;
    int l = tid & 63, w = tid >> 6;
    int wrow = (w >> 1) * 64, wcol = (w & 1) * 64;
    int mn = tid & 31, mk0 = tid >> 5;    // staging decomposition

    f32x16 acc[2][2];
    #pragma unroll
    for (int i = 0; i < 2; ++i)
        #pragma unroll
        for (int j = 0; j < 2; ++j)
            #pragma unroll
            for (int r = 0; r < 16; ++r) acc[i][j][r] = 0.f;

    for (int step = 0; step < 4; ++step) {
        int k0 = step * 64;
        __syncthreads();
        // A: W7 rows (already bf16, k-contiguous)
        #pragma unroll
        for (int e = 0; e < 4; ++e) {
            int slot = tid + 256 * e;
            int r = slot >> 3, sg = slot & 7;
            uint4 v = *(const uint4*)&Wb[(size_t)(cbase + r) * CCH + k0 + sg * 8];
            *(uint4*)&Ws[r * 64 + ((sg ^ (r & 7)) << 3)] = v;
        }
        // B: x fp32 [k][n] -> Xs[n][k] bf16 via 4x4 register transpose
        #pragma unroll
        for (int mi = 0; mi < 2; ++mi) {
            int mk = mk0 + mi * 8;                       // 0..15 -> k-local mk*4..mk*4+3
            const float* sp = &xb[(size_t)(k0 + mk * 4) * NPIX + n0 + mn * 4];
            float4 q0 = *(const float4*)sp;
            float4 q1 = *(const float4*)(sp + NPIX);
            float4 q2 = *(const float4*)(sp + 2 * NPIX);
            float4 q3 = *(const float4*)(sp + 3 * NPIX);
            int klo = mk * 4;
            int unit = klo >> 3, sub = (klo & 7) >> 2;   // sub in {0,1}
            #pragma unroll
            for (int j = 0; j < 4; ++j) {
                float e0 = j == 0 ? q0.x : j == 1 ? q0.y : j == 2 ? q0.z : q0.w;
                float e1 = j == 0 ? q1.x : j == 1 ? q1.y : j == 2 ? q1.z : q1.w;
                float e2 = j == 0 ? q2.x : j == 1 ? q2.y : j == 2 ? q2.z : q2.w;
                float e3 = j == 0 ? q3.x : j == 1 ? q3.y : j == 2 ? q3.z : q3.w;
                int nl = mn * 4 + j;
                ushort4 cv = make_ushort4(bf1(e0), bf1(e1), bf1(e2), bf1(e3));
                int idx = nl * 64 + (((unit) ^ ((nl >> 2) & 7)) << 3) + sub * 4;
                *(ushort4*)&Xs[idx] = cv;
            }
        }
        __syncthreads();
        #pragma unroll
        for (int kk = 0; kk < 4; ++kk) {
            int useg = kk * 2 + (l >> 5);
            bf16x8 af[2], bfr[2];
            #pragma unroll
            for (int at = 0; at < 2; ++at) {
                int c = wrow + at * 32 + (l & 31);
                af[at] = *(const bf16x8*)&Ws[c * 64 + ((useg ^ (c & 7)) << 3)];
            }
            #pragma unroll
            for (int bt = 0; bt < 2; ++bt) {
                int n = wcol + bt * 32 + (l & 31);
                bfr[bt] = *(const bf16x8*)&Xs[n * 64 + ((useg ^ ((n >> 2) & 7)) << 3)];
            }
            #pragma unroll
            for (int at = 0; at < 2; ++at)
                #pragma unroll
                for (int bt = 0; bt < 2; ++bt)
                    acc[at][bt] = __builtin_amdgcn_mfma_f32_32x32x16_bf16(af[at], bfr[bt], acc[at][bt], 0, 0, 0);
        }
    }
    #pragma unroll
    for (int at = 0; at < 2; ++at)
        #pragma unroll
        for (int bt = 0; bt < 2; ++bt)
            #pragma unroll
            for (int r = 0; r < 16; ++r) {
                int c = cbase + wrow + at * 32 + (r & 3) + ((r >> 2) << 3) + ((l >> 5) << 2);
                int n = n0 + wcol + bt * 32 + (l & 31);
                float v = acc[at][bt][r] + b6[b * CCH + c];
                v = v > 0.f ? v : SLOPE * v;
                out[(size_t)b * CCH * NPIX + (size_t)c * NPIX + n] = v;
            }
}

extern "C" void kernel_launch(void* const* d_in, const int* in_sizes, int n_in,
                              void* d_out, int out_size, void* d_ws, size_t ws_size,
                              hipStream_t stream) {
    (void)in_sizes; (void)n_in; (void)out_size; (void)ws_size;
    const float* x      = (const float*)d_in[0];
    const float* se_w1  = (const float*)d_in[1];
    const float* se_w2  = (const float*)d_in[2];
    const float* wq     = (const float*)d_in[3];
    const float* bq     = (const float*)d_in[4];
    const float* wk     = (const float*)d_in[5];
    const float* bk     = (const float*)d_in[6];
    const float* wv     = (const float*)d_in[7];
    const float* bv     = (const float*)d_in[8];
    const float* w_wg   = (const float*)d_in[9];
    const float* w_out  = (const float*)d_in[14];
    const float* b_out  = (const float*)d_in[15];
    float* out = (float*)d_out;
    float* ws = (float*)d_ws;

    hipMemsetAsync(ws + OFF_GX, 0, (size_t)NB * CCH * CCH * sizeof(float), stream);
    mean_kernel<<<NB * CCH, 256, 0, stream>>>(x, ws + OFF_YM);
    se_kernel<<<NB, 256, 0, stream>>>(ws + OFF_YM, se_w1, se_w2, ws + OFF_SC, ws + OFF_RS);
    prep_kernel<<<1, 256, 0, stream>>>((const float*)d_in[10], (const float*)d_in[11],
                                       (const float*)d_in[12], (const float*)d_in[13],
                                       (const float*)d_in[16], (const float*)d_in[17],
                                       (const float*)d_in[18], (const float*)d_in[19],
                                       ws + OFF_SWG, ws + OFF_TWG, ws + OFF_SOUT, ws + OFF_TOUT);
    qsvs_kernel<<<NB, 256, 0, stream>>>(wq, wv, ws + OFF_RS, ws + OFF_QS, ws + OFF_VS);
    gram_mfma_kernel<<<NB * 3 * 32, 256, 0, stream>>>(x, ws + OFF_GX);
    t1_kernel<<<NB * INTR, 256, 0, stream>>>(wq, ws + OFF_SC, ws + OFF_GX, ws + OFF_T1);
    ssoft_kernel<<<NB * INTR, 128, 0, stream>>>(ws + OFF_T1, wv, bq, bv, ws + OFF_QS, ws + OFF_VS, ws + OFF_M);
    wav_kernel<<<NB * INTR, 256, 0, stream>>>(ws + OFF_M, wk, ws + OFF_WAV);
    biaschain_kernel<<<NB, 256, 0, stream>>>(ws + OFF_M, bk, w_wg, ws + OFF_SWG, ws + OFF_TWG,
                                             w_out, b_out, ws + OFF_SOUT, ws + OFF_TOUT, ws + OFF_B6);
    w2_kernel<<<NB * INTR, 256, 0, stream>>>(w_wg, ws + OFF_WAV, ws + OFF_SWG, ws + OFF_W2);
    w7_kernel<<<NB * CCH, 256, 0, stream>>>(w_out, ws + OFF_W2, ws + OFF_SOUT, ws + OFF_SC,
                                            (unsigned short*)(ws + OFF_W7));
    final_mfma_kernel<<<NB * 2 * 128, 256, 0, stream>>>((const unsigned short*)(ws + OFF_W7),
                                                        x, ws + OFF_B6, out);
}

// Round 3
// 345.975 us; speedup vs baseline: 2.3922x; 1.1077x over previous
//
#include <hip/hip_runtime.h>
#include <hip/hip_fp16.h>

#define NPIX 16384
#define CCH 256
#define INTR 128
#define REDD 32
#define NB 8
#define SLOPE 0.1f
#define BNEPS 1e-5f

typedef _Float16 f16x8 __attribute__((ext_vector_type(8)));
typedef __attribute__((ext_vector_type(16))) float f32x16;

// workspace offsets (floats)
#define OFF_GX    0            // 8*256*256 = 524288
#define OFF_YM    524288       // 2048  (raw row sums; memset together with GX)
#define OFF_SC    526336       // 2048
#define OFF_RS    528384       // 2048
#define OFF_QS    530432       // 1024
#define OFF_VS    531456       // 1024
#define OFF_SWG   532480       // 128
#define OFF_TWG   532608       // 128
#define OFF_SOUT  532736       // 256
#define OFF_TOUT  532992       // 256
#define OFF_M     795392       // 8*128*128 = 131072
#define OFF_WAV   926464       // 262144
#define OFF_W2    1188608      // 262144
#define OFF_W7    1450752      // ushort f16 [8*256*256] = 1 MB
#define OFF_B6    1975040      // 2048

__device__ __forceinline__ unsigned short h1(float f) {
    __half h = __float2half(f);
    return __half_as_ushort(h);
}

__device__ __forceinline__ uint4 cvt8h(const float4 a, const float4 c) {
    __half2 p0 = __floats2half2_rn(a.x, a.y);
    __half2 p1 = __floats2half2_rn(a.z, a.w);
    __half2 p2 = __floats2half2_rn(c.x, c.y);
    __half2 p3 = __floats2half2_rn(c.z, c.w);
    uint4 r;
    r.x = *(unsigned int*)&p0; r.y = *(unsigned int*)&p1;
    r.z = *(unsigned int*)&p2; r.w = *(unsigned int*)&p3;
    return r;
}

// ---------- 2. SE block (reads raw row sums) -> scale[b,c], rsum[b,c]=sg*rowsum ----------
__global__ __launch_bounds__(256) void se_kernel(const float* __restrict__ ymsum,
                                                 const float* __restrict__ se_w1,
                                                 const float* __restrict__ se_w2,
                                                 float* __restrict__ scale,
                                                 float* __restrict__ rsum) {
    int b = blockIdx.x, t = threadIdx.x;
    __shared__ float ys[CCH];
    __shared__ float y1s[REDD];
    float ymr = ymsum[b * CCH + t];
    ys[t] = ymr * (1.f / 16384.f);
    __syncthreads();
    if (t < REDD) {
        float a = 0.f;
        #pragma unroll 4
        for (int c = 0; c < CCH; ++c) a += se_w1[t * CCH + c] * ys[c];
        y1s[t] = a > 0.f ? a : SLOPE * a;
    }
    __syncthreads();
    float a = 0.f;
    #pragma unroll
    for (int r = 0; r < REDD; ++r) a += se_w2[t * REDD + r] * y1s[r];
    float sg = 1.f / (1.f + expf(-a));
    scale[b * CCH + t] = sg;
    rsum[b * CCH + t] = sg * ymr;
}

// ---------- 3. BN constant folding ----------
__global__ __launch_bounds__(256) void prep_kernel(const float* __restrict__ g_wg, const float* __restrict__ be_wg,
                                                   const float* __restrict__ rm_wg, const float* __restrict__ rv_wg,
                                                   const float* __restrict__ g_out, const float* __restrict__ be_out,
                                                   const float* __restrict__ rm_out, const float* __restrict__ rv_out,
                                                   float* __restrict__ swg, float* __restrict__ twg,
                                                   float* __restrict__ sout, float* __restrict__ tout) {
    int t = threadIdx.x;
    if (t < INTR) {
        float s = g_wg[t] / sqrtf(rv_wg[t] + BNEPS);
        swg[t] = s;
        twg[t] = be_wg[t] - rm_wg[t] * s;
    }
    float s = g_out[t] / sqrtf(rv_out[t] + BNEPS);
    sout[t] = s;
    tout[t] = be_out[t] - rm_out[t] * s;
}

// ---------- 4. qs[b,i]=Wq.rsum, vs[b,j]=Wv.rsum ----------
__global__ __launch_bounds__(256) void qsvs_kernel(const float* __restrict__ wq,
                                                   const float* __restrict__ wv,
                                                   const float* __restrict__ rsum,
                                                   float* __restrict__ qs, float* __restrict__ vs) {
    int b = blockIdx.x, t = threadIdx.x;
    __shared__ float rs[CCH];
    rs[t] = rsum[b * CCH + t];
    __syncthreads();
    const float* w = (t < INTR) ? (wq + t * CCH) : (wv + (t - INTR) * CCH);
    float a = 0.f;
    #pragma unroll 4
    for (int c = 0; c < CCH; ++c) a += w[c] * rs[c];
    if (t < INTR) qs[b * INTR + t] = a;
    else          vs[b * INTR + (t - INTR)] = a;
}

// ---------- 5. Gram via MFMA f16 + fused row sums ----------
__global__ __launch_bounds__(256, 4) void gram_mfma_kernel(const float* __restrict__ x,
                                                           float* __restrict__ Gx,
                                                           float* __restrict__ ymsum) {
    __shared__ __align__(16) unsigned short Ah[128 * 64];
    __shared__ __align__(16) unsigned short Bh[128 * 64];
    int bid = blockIdx.x;
    int chunk = bid & 31;            // 32 chunks of 512 pixels
    int t2 = bid >> 5;
    int tile = t2 % 3;               // 0:(0,0) 1:(128,128) 2:(0,128)+mirror
    int b = t2 / 3;
    int rowbase = (tile == 1) ? 128 : 0;
    int colbase = (tile == 0) ? 0 : 128;
    bool diag = (tile < 2);
    const float* xb = x + (size_t)b * CCH * NPIX;
    int n0 = chunk * 512;
    int tid = threadIdx.x;
    int l = tid & 63, w = tid >> 6;
    int wrow = (w >> 1) * 64, wcol = (w & 1) * 64;

    f32x16 acc[2][2];
    #pragma unroll
    for (int i = 0; i < 2; ++i)
        #pragma unroll
        for (int j = 0; j < 2; ++j)
            #pragma unroll
            for (int r = 0; r < 16; ++r) acc[i][j][r] = 0.f;
    float rowacc[4] = {0.f, 0.f, 0.f, 0.f};

    for (int step = 0; step < 8; ++step) {
        int k0 = n0 + step * 64;
        __syncthreads();
        #pragma unroll
        for (int e = 0; e < 4; ++e) {
            int slot = tid + 256 * e;
            int r = slot >> 3, sg = slot & 7;
            const float* src = &xb[(size_t)(rowbase + r) * NPIX + k0 + sg * 8];
            float4 v0 = *(const float4*)src;
            float4 v1 = *(const float4*)(src + 4);
            if (diag) rowacc[e] += (v0.x + v0.y) + (v0.z + v0.w) + (v1.x + v1.y) + (v1.z + v1.w);
            int dst = r * 64 + ((sg ^ (r & 7)) << 3);
            *(uint4*)&Ah[dst] = cvt8h(v0, v1);
            if (!diag) {
                const float* src2 = &xb[(size_t)(colbase + r) * NPIX + k0 + sg * 8];
                float4 u0 = *(const float4*)src2;
                float4 u1 = *(const float4*)(src2 + 4);
                *(uint4*)&Bh[dst] = cvt8h(u0, u1);
            }
        }
        __syncthreads();
        const unsigned short* BP = diag ? Ah : Bh;
        #pragma unroll
        for (int kk = 0; kk < 4; ++kk) {
            int useg = kk * 2 + (l >> 5);
            f16x8 af[2], bf[2];
            #pragma unroll
            for (int at = 0; at < 2; ++at) {
                int r = wrow + at * 32 + (l & 31);
                af[at] = *(const f16x8*)&Ah[r * 64 + ((useg ^ (r & 7)) << 3)];
            }
            #pragma unroll
            for (int bt = 0; bt < 2; ++bt) {
                int c = wcol + bt * 32 + (l & 31);
                bf[bt] = *(const f16x8*)&BP[c * 64 + ((useg ^ (c & 7)) << 3)];
            }
            #pragma unroll
            for (int at = 0; at < 2; ++at)
                #pragma unroll
                for (int bt = 0; bt < 2; ++bt)
                    acc[at][bt] = __builtin_amdgcn_mfma_f32_32x32x16_f16(af[at], bf[bt], acc[at][bt], 0, 0, 0);
        }
    }
    float* G = Gx + (size_t)b * CCH * CCH;
    #pragma unroll
    for (int at = 0; at < 2; ++at)
        #pragma unroll
        for (int bt = 0; bt < 2; ++bt)
            #pragma unroll
            for (int r = 0; r < 16; ++r) {
                int gr = rowbase + wrow + at * 32 + (r & 3) + ((r >> 2) << 3) + ((l >> 5) << 2);
                int gc = colbase + wcol + bt * 32 + (l & 31);
                float v = acc[at][bt][r];
                atomicAdd(&G[gr * CCH + gc], v);
                if (tile == 2) atomicAdd(&G[gc * CCH + gr], v);
            }
    if (diag) {
        #pragma unroll
        for (int e = 0; e < 4; ++e) {
            float s = rowacc[e];
            s += __shfl_xor(s, 1);
            s += __shfl_xor(s, 2);
            s += __shfl_xor(s, 4);
            if ((tid & 7) == 0) {
                int r = (tid + 256 * e) >> 3;
                atomicAdd(&ymsum[b * CCH + rowbase + r], s);
            }
        }
    }
}

// ---------- 6+7 fused: T1 row (in LDS) -> S row -> softmax -> M[b,j,i] ----------
__global__ __launch_bounds__(256) void ts_kernel(const float* __restrict__ wq,
                                                 const float* __restrict__ scale,
                                                 const float* __restrict__ Gx,
                                                 const float* __restrict__ wv,
                                                 const float* __restrict__ bq,
                                                 const float* __restrict__ bv,
                                                 const float* __restrict__ qs,
                                                 const float* __restrict__ vs,
                                                 float* __restrict__ M) {
    int bid = blockIdx.x;
    int i = bid & 127, b = bid >> 7;
    int t = threadIdx.x;
    __shared__ float sw[CCH];
    __shared__ float t1s[CCH];
    __shared__ float part[256];
    __shared__ float redm[2], reds[2];
    sw[t] = wq[i * CCH + t] * scale[b * CCH + t];
    __syncthreads();
    const float* G = Gx + (size_t)b * CCH * CCH;
    float acc = 0.f;
    #pragma unroll 4
    for (int c = 0; c < CCH; ++c) acc += sw[c] * G[c * CCH + t];
    t1s[t] = acc * scale[b * CCH + t];
    __syncthreads();
    int j = t & 127, h = t >> 7;
    const float* wvr = wv + j * CCH + h * 128;
    const float* tp = t1s + h * 128;
    float p = 0.f;
    #pragma unroll 4
    for (int c = 0; c < 128; ++c) p += tp[c] * wvr[c];
    part[t] = p;
    __syncthreads();
    float acc2 = 0.f;
    if (t < 128)
        acc2 = part[t] + part[t + 128]
             + bq[i] * vs[b * INTR + j] + bv[j] * qs[b * INTR + i] + 16384.f * bq[i] * bv[j];
    float m = acc2;
    for (int off = 32; off > 0; off >>= 1) m = fmaxf(m, __shfl_xor(m, off));
    if (t == 0) redm[0] = m;
    if (t == 64) redm[1] = m;
    __syncthreads();
    m = fmaxf(redm[0], redm[1]);
    float e = expf(acc2 - m);
    float s = e;
    for (int off = 32; off > 0; off >>= 1) s += __shfl_xor(s, off);
    if (t == 0) reds[0] = s;
    if (t == 64) reds[1] = s;
    __syncthreads();
    s = reds[0] + reds[1];
    if (t < 128)
        M[(size_t)b * INTR * INTR + j * INTR + i] = e / s;   // transposed store
}

// ---------- 8. Wav[b,i,c] = sum_j M[b,i,j]*wk[j,c] ----------
__global__ __launch_bounds__(256) void wav_kernel(const float* __restrict__ M,
                                                  const float* __restrict__ wk,
                                                  float* __restrict__ Wav) {
    int bid = blockIdx.x;
    int i = bid & 127, b = bid >> 7;
    int t = threadIdx.x;
    __shared__ float ms[INTR];
    if (t < INTR) ms[t] = M[(size_t)b * INTR * INTR + i * INTR + t];
    __syncthreads();
    float acc = 0.f;
    #pragma unroll 4
    for (int jj = 0; jj < INTR; ++jj) acc += ms[jj] * wk[jj * CCH + t];
    Wav[(size_t)b * INTR * CCH + i * CCH + t] = acc;
}

// ---------- 9. bias chain -> b6[b,c] ----------
__global__ __launch_bounds__(256) void biaschain_kernel(const float* __restrict__ M,
                                                        const float* __restrict__ bk,
                                                        const float* __restrict__ wwg,
                                                        const float* __restrict__ swg,
                                                        const float* __restrict__ twg,
                                                        const float* __restrict__ wout,
                                                        const float* __restrict__ bout,
                                                        const float* __restrict__ sout,
                                                        const float* __restrict__ tout,
                                                        float* __restrict__ b6) {
    int b = blockIdx.x, t = threadIdx.x;
    __shared__ float bavs[INTR], b2s[INTR];
    if (t < INTR) {
        float a = 0.f;
        #pragma unroll 4
        for (int j = 0; j < INTR; ++j) a += M[(size_t)b * INTR * INTR + t * INTR + j] * bk[j];
        bavs[t] = a;
    }
    __syncthreads();
    if (t < INTR) {
        float a = 0.f;
        #pragma unroll 4
        for (int i = 0; i < INTR; ++i) a += wwg[t * INTR + i] * bavs[i];
        b2s[t] = swg[t] * a + twg[t];
    }
    __syncthreads();
    float a = 0.f;
    #pragma unroll 4
    for (int o = 0; o < INTR; ++o) a += wout[t * INTR + o] * b2s[o];
    float b5 = a + bout[t];
    b6[b * CCH + t] = sout[t] * b5 + tout[t];
}

// ---------- 10. W2[b,o,c] = swg[o]*sum_i wwg[o,i]*Wav[b,i,c] ----------
__global__ __launch_bounds__(256) void w2_kernel(const float* __restrict__ wwg,
                                                 const float* __restrict__ Wav,
                                                 const float* __restrict__ swg,
                                                 float* __restrict__ W2) {
    int bid = blockIdx.x;
    int o = bid & 127, b = bid >> 7;
    int t = threadIdx.x;
    __shared__ float wr[INTR];
    if (t < INTR) wr[t] = wwg[o * INTR + t];
    __syncthreads();
    float acc = 0.f;
    #pragma unroll 4
    for (int i = 0; i < INTR; ++i) acc += wr[i] * Wav[(size_t)b * INTR * CCH + i * CCH + t];
    W2[(size_t)b * INTR * CCH + o * CCH + t] = swg[o] * acc;
}

// ---------- 11. W7f16[b,c,c'] = f16((sout[c]*sum_o wout[c,o]*W2[b,o,c'] + I)*scale[b,c']) ----------
__global__ __launch_bounds__(256) void w7_kernel(const float* __restrict__ wout,
                                                 const float* __restrict__ W2,
                                                 const float* __restrict__ sout,
                                                 const float* __restrict__ scale,
                                                 unsigned short* __restrict__ W7h) {
    int bid = blockIdx.x;
    int c = bid & 255, b = bid >> 8;
    int t = threadIdx.x;
    __shared__ float wr[INTR];
    if (t < INTR) wr[t] = wout[c * INTR + t];
    __syncthreads();
    float acc = 0.f;
    #pragma unroll 4
    for (int o = 0; o < INTR; ++o) acc += wr[o] * W2[(size_t)b * INTR * CCH + o * CCH + t];
    float w6 = sout[c] * acc + ((c == t) ? 1.f : 0.f);
    W7h[(size_t)b * CCH * CCH + c * CCH + t] = h1(w6 * scale[b * CCH + t]);
}

// ---------- 12. out = leaky(W7 @ x + b6) via MFMA f16 ----------
__global__ __launch_bounds__(256, 4) void final_mfma_kernel(const unsigned short* __restrict__ W7h,
                                                            const float* __restrict__ x,
                                                            const float* __restrict__ b6,
                                                            float* __restrict__ out) {
    __shared__ __align__(16) unsigned short Ws[128 * 64];
    __shared__ __align__(16) unsigned short Xs[128 * 64];
    int bid = blockIdx.x;
    int ct = bid & 1;
    int nt = (bid >> 1) & 127;
    int b = bid >> 8;
    int cbase = ct * 128, n0 = nt * 128;
    const float* xb = x + (size_t)b * CCH * NPIX;
    const unsigned short* Wb = W7h + (size_t)b * CCH * CCH;
    int tid = threadIdx.x;
    int l = tid & 63, w = tid >> 6;
    int wrow = (w >> 1) * 64, wcol = (w & 1) * 64;
    int mn = tid & 31, mk0 = tid >> 5;

    f32x16 acc[2][2];
    #pragma unroll
    for (int i = 0; i < 2; ++i)
        #pragma unroll
        for (int j = 0; j < 2; ++j)
            #pragma unroll
            for (int r = 0; r < 16; ++r) acc[i][j][r] = 0.f;

    for (int step = 0; step < 4; ++step) {
        int k0 = step * 64;
        __syncthreads();
        // A: W7 rows (f16, k-contiguous)
        #pragma unroll
        for (int e = 0; e < 4; ++e) {
            int slot = tid + 256 * e;
            int r = slot >> 3, sg = slot & 7;
            uint4 v = *(const uint4*)&Wb[(size_t)(cbase + r) * CCH + k0 + sg * 8];
            *(uint4*)&Ws[r * 64 + ((sg ^ (r & 7)) << 3)] = v;
        }
        // B: x fp32 [k][n] -> Xs[n][k] f16 via 4x4 register transpose
        #pragma unroll
        for (int mi = 0; mi < 2; ++mi) {
            int mk = mk0 + mi * 8;
            const float* sp = &xb[(size_t)(k0 + mk * 4) * NPIX + n0 + mn * 4];
            float4 q0 = *(const float4*)sp;
            float4 q1 = *(const float4*)(sp + NPIX);
            float4 q2 = *(const float4*)(sp + 2 * NPIX);
            float4 q3 = *(const float4*)(sp + 3 * NPIX);
            int klo = mk * 4;
            int unit = klo >> 3, sub = (klo & 7) >> 2;
            #pragma unroll
            for (int j = 0; j < 4; ++j) {
                float e0 = j == 0 ? q0.x : j == 1 ? q0.y : j == 2 ? q0.z : q0.w;
                float e1 = j == 0 ? q1.x : j == 1 ? q1.y : j == 2 ? q1.z : q1.w;
                float e2 = j == 0 ? q2.x : j == 1 ? q2.y : j == 2 ? q2.z : q2.w;
                float e3 = j == 0 ? q3.x : j == 1 ? q3.y : j == 2 ? q3.z : q3.w;
                int nl = mn * 4 + j;
                ushort4 cv = make_ushort4(h1(e0), h1(e1), h1(e2), h1(e3));
                int idx = nl * 64 + ((unit ^ ((nl >> 2) & 7)) << 3) + sub * 4;
                *(ushort4*)&Xs[idx] = cv;
            }
        }
        __syncthreads();
        #pragma unroll
        for (int kk = 0; kk < 4; ++kk) {
            int useg = kk * 2 + (l >> 5);
            f16x8 af[2], bfr[2];
            #pragma unroll
            for (int at = 0; at < 2; ++at) {
                int c = wrow + at * 32 + (l & 31);
                af[at] = *(const f16x8*)&Ws[c * 64 + ((useg ^ (c & 7)) << 3)];
            }
            #pragma unroll
            for (int bt = 0; bt < 2; ++bt) {
                int n = wcol + bt * 32 + (l & 31);
                bfr[bt] = *(const f16x8*)&Xs[n * 64 + ((useg ^ ((n >> 2) & 7)) << 3)];
            }
            #pragma unroll
            for (int at = 0; at < 2; ++at)
                #pragma unroll
                for (int bt = 0; bt < 2; ++bt)
                    acc[at][bt] = __builtin_amdgcn_mfma_f32_32x32x16_f16(af[at], bfr[bt], acc[at][bt], 0, 0, 0);
        }
    }
    #pragma unroll
    for (int at = 0; at < 2; ++at)
        #pragma unroll
        for (int bt = 0; bt < 2; ++bt)
            #pragma unroll
            for (int r = 0; r < 16; ++r) {
                int c = cbase + wrow + at * 32 + (r & 3) + ((r >> 2) << 3) + ((l >> 5) << 2);
                int n = n0 + wcol + bt * 32 + (l & 31);
                float v = acc[at][bt][r] + b6[b * CCH + c];
                v = v > 0.f ? v : SLOPE * v;
                out[(size_t)b * CCH * NPIX + (size_t)c * NPIX + n] = v;
            }
}

extern "C" void kernel_launch(void* const* d_in, const int* in_sizes, int n_in,
                              void* d_out, int out_size, void* d_ws, size_t ws_size,
                              hipStream_t stream) {
    (void)in_sizes; (void)n_in; (void)out_size; (void)ws_size;
    const float* x      = (const float*)d_in[0];
    const float* se_w1  = (const float*)d_in[1];
    const float* se_w2  = (const float*)d_in[2];
    const float* wq     = (const float*)d_in[3];
    const float* bq     = (const float*)d_in[4];
    const float* wk     = (const float*)d_in[5];
    const float* bk     = (const float*)d_in[6];
    const float* wv     = (const float*)d_in[7];
    const float* bv     = (const float*)d_in[8];
    const float* w_wg   = (const float*)d_in[9];
    const float* w_out  = (const float*)d_in[14];
    const float* b_out  = (const float*)d_in[15];
    float* out = (float*)d_out;
    float* ws = (float*)d_ws;

    // zero G + row-sum accumulators (contiguous)
    hipMemsetAsync(ws + OFF_GX, 0, (size_t)(NB * CCH * CCH + NB * CCH) * sizeof(float), stream);
    gram_mfma_kernel<<<NB * 3 * 32, 256, 0, stream>>>(x, ws + OFF_GX, ws + OFF_YM);
    se_kernel<<<NB, 256, 0, stream>>>(ws + OFF_YM, se_w1, se_w2, ws + OFF_SC, ws + OFF_RS);
    prep_kernel<<<1, 256, 0, stream>>>((const float*)d_in[10], (const float*)d_in[11],
                                       (const float*)d_in[12], (const float*)d_in[13],
                                       (const float*)d_in[16], (const float*)d_in[17],
                                       (const float*)d_in[18], (const float*)d_in[19],
                                       ws + OFF_SWG, ws + OFF_TWG, ws + OFF_SOUT, ws + OFF_TOUT);
    qsvs_kernel<<<NB, 256, 0, stream>>>(wq, wv, ws + OFF_RS, ws + OFF_QS, ws + OFF_VS);
    ts_kernel<<<NB * INTR, 256, 0, stream>>>(wq, ws + OFF_SC, ws + OFF_GX, wv, bq, bv,
                                             ws + OFF_QS, ws + OFF_VS, ws + OFF_M);
    wav_kernel<<<NB * INTR, 256, 0, stream>>>(ws + OFF_M, wk, ws + OFF_WAV);
    biaschain_kernel<<<NB, 256, 0, stream>>>(ws + OFF_M, bk, w_wg, ws + OFF_SWG, ws + OFF_TWG,
                                             w_out, b_out, ws + OFF_SOUT, ws + OFF_TOUT, ws + OFF_B6);
    w2_kernel<<<NB * INTR, 256, 0, stream>>>(w_wg, ws + OFF_WAV, ws + OFF_SWG, ws + OFF_W2);
    w7_kernel<<<NB * CCH, 256, 0, stream>>>(w_out, ws + OFF_W2, ws + OFF_SOUT, ws + OFF_SC,
                                            (unsigned short*)(ws + OFF_W7));
    final_mfma_kernel<<<NB * 2 * 128, 256, 0, stream>>>((const unsigned short*)(ws + OFF_W7),
                                                        x, ws + OFF_B6, out);
}

// Round 4
// 247.578 us; speedup vs baseline: 3.3430x; 1.3974x over previous
//
#include <hip/hip_runtime.h>
#include <hip/hip_fp16.h>

#define NPIX 16384
#define CCH 256
#define INTR 128
#define REDD 32
#define NB 8
#define SLOPE 0.1f
#define BNEPS 1e-5f

typedef _Float16 f16x8 __attribute__((ext_vector_type(8)));
typedef __attribute__((ext_vector_type(16))) float f32x16;

// workspace offsets (floats)
#define OFF_GX    0            // 8*256*256 = 524288
#define OFF_YM    524288       // 2048  (raw row sums; memset before gram)
#define OFF_SC    526336       // 2048
#define OFF_RS    528384       // 2048
#define OFF_QS    530432       // 1024
#define OFF_VS    531456       // 1024
#define OFF_SWG   532480       // 128
#define OFF_TWG   532608       // 128
#define OFF_SOUT  532736       // 256
#define OFF_TOUT  532992       // 256
#define OFF_M     795392       // 8*128*128 = 131072
#define OFF_WAV   926464       // 262144
#define OFF_W2    1188608      // 262144
#define OFF_W7    1450752      // ushort f16 [8*256*256] = 1 MB
#define OFF_B6    1975040      // 2048
// Gram split-K partials overlay OFF_M.. (dead until ts_kernel); extent checked vs ws_size
#define OFF_PART  OFF_M

__device__ __forceinline__ unsigned short h1(float f) {
    __half h = __float2half(f);
    return __half_as_ushort(h);
}

__device__ __forceinline__ uint4 cvt8h(const float4 a, const float4 c) {
    __half2 p0 = __floats2half2_rn(a.x, a.y);
    __half2 p1 = __floats2half2_rn(a.z, a.w);
    __half2 p2 = __floats2half2_rn(c.x, c.y);
    __half2 p3 = __floats2half2_rn(c.z, c.w);
    uint4 r;
    r.x = *(unsigned int*)&p0; r.y = *(unsigned int*)&p1;
    r.z = *(unsigned int*)&p2; r.w = *(unsigned int*)&p3;
    return r;
}

// ---------- 2. SE block (reads raw row sums) ----------
__global__ __launch_bounds__(256) void se_kernel(const float* __restrict__ ymsum,
                                                 const float* __restrict__ se_w1,
                                                 const float* __restrict__ se_w2,
                                                 float* __restrict__ scale,
                                                 float* __restrict__ rsum) {
    int b = blockIdx.x, t = threadIdx.x;
    __shared__ float ys[CCH];
    __shared__ float y1s[REDD];
    float ymr = ymsum[b * CCH + t];
    ys[t] = ymr * (1.f / 16384.f);
    __syncthreads();
    if (t < REDD) {
        float a = 0.f;
        #pragma unroll 4
        for (int c = 0; c < CCH; ++c) a += se_w1[t * CCH + c] * ys[c];
        y1s[t] = a > 0.f ? a : SLOPE * a;
    }
    __syncthreads();
    float a = 0.f;
    #pragma unroll
    for (int r = 0; r < REDD; ++r) a += se_w2[t * REDD + r] * y1s[r];
    float sg = 1.f / (1.f + expf(-a));
    scale[b * CCH + t] = sg;
    rsum[b * CCH + t] = sg * ymr;
}

// ---------- 3. BN constant folding ----------
__global__ __launch_bounds__(256) void prep_kernel(const float* __restrict__ g_wg, const float* __restrict__ be_wg,
                                                   const float* __restrict__ rm_wg, const float* __restrict__ rv_wg,
                                                   const float* __restrict__ g_out, const float* __restrict__ be_out,
                                                   const float* __restrict__ rm_out, const float* __restrict__ rv_out,
                                                   float* __restrict__ swg, float* __restrict__ twg,
                                                   float* __restrict__ sout, float* __restrict__ tout) {
    int t = threadIdx.x;
    if (t < INTR) {
        float s = g_wg[t] / sqrtf(rv_wg[t] + BNEPS);
        swg[t] = s;
        twg[t] = be_wg[t] - rm_wg[t] * s;
    }
    float s = g_out[t] / sqrtf(rv_out[t] + BNEPS);
    sout[t] = s;
    tout[t] = be_out[t] - rm_out[t] * s;
}

// ---------- 4. qs/vs ----------
__global__ __launch_bounds__(256) void qsvs_kernel(const float* __restrict__ wq,
                                                   const float* __restrict__ wv,
                                                   const float* __restrict__ rsum,
                                                   float* __restrict__ qs, float* __restrict__ vs) {
    int b = blockIdx.x, t = threadIdx.x;
    __shared__ float rs[CCH];
    rs[t] = rsum[b * CCH + t];
    __syncthreads();
    const float* w = (t < INTR) ? (wq + t * CCH) : (wv + (t - INTR) * CCH);
    float a = 0.f;
    #pragma unroll 4
    for (int c = 0; c < CCH; ++c) a += w[c] * rs[c];
    if (t < INTR) qs[b * INTR + t] = a;
    else          vs[b * INTR + (t - INTR)] = a;
}

// ---------- 5a. Gram split-K partials (NO atomics) + fused row sums ----------
__global__ __launch_bounds__(256, 4) void gram_partial_kernel(const float* __restrict__ x,
                                                              float* __restrict__ partials,
                                                              float* __restrict__ ymsum,
                                                              int nch) {
    __shared__ __align__(16) unsigned short Ah[128 * 64];
    __shared__ __align__(16) unsigned short Bh[128 * 64];
    int bid = blockIdx.x;
    int chunk = bid % nch;
    int t2 = bid / nch;
    int tile = t2 % 3;               // 0:(0,0) 1:(128,128) 2:(0,128)
    int b = t2 / 3;
    int rowbase = (tile == 1) ? 128 : 0;
    int colbase = (tile == 0) ? 0 : 128;
    bool diag = (tile < 2);
    const float* xb = x + (size_t)b * CCH * NPIX;
    int kpb = NPIX / nch;
    int n0 = chunk * kpb;
    int nsteps = kpb >> 6;
    int tid = threadIdx.x;
    int l = tid & 63, w = tid >> 6;
    int wrow = (w >> 1) * 64, wcol = (w & 1) * 64;

    f32x16 acc[2][2];
    #pragma unroll
    for (int i = 0; i < 2; ++i)
        #pragma unroll
        for (int j = 0; j < 2; ++j)
            #pragma unroll
            for (int r = 0; r < 16; ++r) acc[i][j][r] = 0.f;
    float rowacc[4] = {0.f, 0.f, 0.f, 0.f};

    for (int step = 0; step < nsteps; ++step) {
        int k0 = n0 + step * 64;
        __syncthreads();
        #pragma unroll
        for (int e = 0; e < 4; ++e) {
            int slot = tid + 256 * e;
            int r = slot >> 3, sg = slot & 7;
            const float* src = &xb[(size_t)(rowbase + r) * NPIX + k0 + sg * 8];
            float4 v0 = *(const float4*)src;
            float4 v1 = *(const float4*)(src + 4);
            if (diag) rowacc[e] += (v0.x + v0.y) + (v0.z + v0.w) + (v1.x + v1.y) + (v1.z + v1.w);
            int dst = r * 64 + ((sg ^ (r & 7)) << 3);
            *(uint4*)&Ah[dst] = cvt8h(v0, v1);
            if (!diag) {
                const float* src2 = &xb[(size_t)(colbase + r) * NPIX + k0 + sg * 8];
                float4 u0 = *(const float4*)src2;
                float4 u1 = *(const float4*)(src2 + 4);
                *(uint4*)&Bh[dst] = cvt8h(u0, u1);
            }
        }
        __syncthreads();
        const unsigned short* BP = diag ? Ah : Bh;
        #pragma unroll
        for (int kk = 0; kk < 4; ++kk) {
            int useg = kk * 2 + (l >> 5);
            f16x8 af[2], bf[2];
            #pragma unroll
            for (int at = 0; at < 2; ++at) {
                int r = wrow + at * 32 + (l & 31);
                af[at] = *(const f16x8*)&Ah[r * 64 + ((useg ^ (r & 7)) << 3)];
            }
            #pragma unroll
            for (int bt = 0; bt < 2; ++bt) {
                int c = wcol + bt * 32 + (l & 31);
                bf[bt] = *(const f16x8*)&BP[c * 64 + ((useg ^ (c & 7)) << 3)];
            }
            #pragma unroll
            for (int at = 0; at < 2; ++at)
                #pragma unroll
                for (int bt = 0; bt < 2; ++bt)
                    acc[at][bt] = __builtin_amdgcn_mfma_f32_32x32x16_f16(af[at], bf[bt], acc[at][bt], 0, 0, 0);
        }
    }
    // streaming partial store (no atomics)
    float* P = partials + (size_t)bid * (128 * 128);
    #pragma unroll
    for (int at = 0; at < 2; ++at)
        #pragma unroll
        for (int bt = 0; bt < 2; ++bt)
            #pragma unroll
            for (int r = 0; r < 16; ++r) {
                int lr = wrow + at * 32 + (r & 3) + ((r >> 2) << 3) + ((l >> 5) << 2);
                int lc = wcol + bt * 32 + (l & 31);
                P[lr * 128 + lc] = acc[at][bt][r];
            }
    if (diag) {
        #pragma unroll
        for (int e = 0; e < 4; ++e) {
            float s = rowacc[e];
            s += __shfl_xor(s, 1);
            s += __shfl_xor(s, 2);
            s += __shfl_xor(s, 4);
            if ((tid & 7) == 0) {
                int r = (tid + 256 * e) >> 3;
                atomicAdd(&ymsum[b * CCH + rowbase + r], s);
            }
        }
    }
}

// ---------- 5b. reduce partials -> G (float4 per thread) ----------
__global__ __launch_bounds__(256) void gram_reduce_kernel(const float* __restrict__ partials,
                                                          float* __restrict__ Gx,
                                                          int nch) {
    int bid = blockIdx.x;
    int part = bid & 15;              // 16 x 1024 elems = 16384
    int tileIdx = bid >> 4;           // b*3 + tile
    int tile = tileIdx % 3;
    int b = tileIdx / 3;
    int rowbase = (tile == 1) ? 128 : 0;
    int colbase = (tile == 0) ? 0 : 128;
    int locIdx = part * 1024 + threadIdx.x * 4;
    const float* P = partials + (size_t)tileIdx * nch * (128 * 128) + locIdx;
    float4 s = make_float4(0.f, 0.f, 0.f, 0.f);
    for (int ch = 0; ch < nch; ++ch) {
        float4 v = *(const float4*)(P + (size_t)ch * (128 * 128));
        s.x += v.x; s.y += v.y; s.z += v.z; s.w += v.w;
    }
    int lr = locIdx >> 7, lc = locIdx & 127;
    float* G = Gx + (size_t)b * CCH * CCH;
    *(float4*)&G[(rowbase + lr) * CCH + colbase + lc] = s;
    if (tile == 2) {
        G[(colbase + lc + 0) * CCH + rowbase + lr] = s.x;
        G[(colbase + lc + 1) * CCH + rowbase + lr] = s.y;
        G[(colbase + lc + 2) * CCH + rowbase + lr] = s.z;
        G[(colbase + lc + 3) * CCH + rowbase + lr] = s.w;
    }
}

// ---------- 6+7 fused: T1 row -> S row -> softmax -> M[b,j,i] ----------
__global__ __launch_bounds__(256) void ts_kernel(const float* __restrict__ wq,
                                                 const float* __restrict__ scale,
                                                 const float* __restrict__ Gx,
                                                 const float* __restrict__ wv,
                                                 const float* __restrict__ bq,
                                                 const float* __restrict__ bv,
                                                 const float* __restrict__ qs,
                                                 const float* __restrict__ vs,
                                                 float* __restrict__ M) {
    int bid = blockIdx.x;
    int i = bid & 127, b = bid >> 7;
    int t = threadIdx.x;
    __shared__ float sw[CCH];
    __shared__ float t1s[CCH];
    __shared__ float part[256];
    __shared__ float redm[2], reds[2];
    sw[t] = wq[i * CCH + t] * scale[b * CCH + t];
    __syncthreads();
    const float* G = Gx + (size_t)b * CCH * CCH;
    float acc = 0.f;
    #pragma unroll 4
    for (int c = 0; c < CCH; ++c) acc += sw[c] * G[c * CCH + t];
    t1s[t] = acc * scale[b * CCH + t];
    __syncthreads();
    int j = t & 127, h = t >> 7;
    const float* wvr = wv + j * CCH + h * 128;
    const float* tp = t1s + h * 128;
    float p = 0.f;
    #pragma unroll 4
    for (int c = 0; c < 128; ++c) p += tp[c] * wvr[c];
    part[t] = p;
    __syncthreads();
    float acc2 = 0.f;
    if (t < 128)
        acc2 = part[t] + part[t + 128]
             + bq[i] * vs[b * INTR + j] + bv[j] * qs[b * INTR + i] + 16384.f * bq[i] * bv[j];
    float m = acc2;
    for (int off = 32; off > 0; off >>= 1) m = fmaxf(m, __shfl_xor(m, off));
    if (t == 0) redm[0] = m;
    if (t == 64) redm[1] = m;
    __syncthreads();
    m = fmaxf(redm[0], redm[1]);
    float e = expf(acc2 - m);
    float s = e;
    for (int off = 32; off > 0; off >>= 1) s += __shfl_xor(s, off);
    if (t == 0) reds[0] = s;
    if (t == 64) reds[1] = s;
    __syncthreads();
    s = reds[0] + reds[1];
    if (t < 128)
        M[(size_t)b * INTR * INTR + j * INTR + i] = e / s;   // transposed store
}

// ---------- 8. Wav ----------
__global__ __launch_bounds__(256) void wav_kernel(const float* __restrict__ M,
                                                  const float* __restrict__ wk,
                                                  float* __restrict__ Wav) {
    int bid = blockIdx.x;
    int i = bid & 127, b = bid >> 7;
    int t = threadIdx.x;
    __shared__ float ms[INTR];
    if (t < INTR) ms[t] = M[(size_t)b * INTR * INTR + i * INTR + t];
    __syncthreads();
    float acc = 0.f;
    #pragma unroll 4
    for (int jj = 0; jj < INTR; ++jj) acc += ms[jj] * wk[jj * CCH + t];
    Wav[(size_t)b * INTR * CCH + i * CCH + t] = acc;
}

// ---------- 9. bias chain ----------
__global__ __launch_bounds__(256) void biaschain_kernel(const float* __restrict__ M,
                                                        const float* __restrict__ bk,
                                                        const float* __restrict__ wwg,
                                                        const float* __restrict__ swg,
                                                        const float* __restrict__ twg,
                                                        const float* __restrict__ wout,
                                                        const float* __restrict__ bout,
                                                        const float* __restrict__ sout,
                                                        const float* __restrict__ tout,
                                                        float* __restrict__ b6) {
    int b = blockIdx.x, t = threadIdx.x;
    __shared__ float bavs[INTR], b2s[INTR];
    if (t < INTR) {
        float a = 0.f;
        #pragma unroll 4
        for (int j = 0; j < INTR; ++j) a += M[(size_t)b * INTR * INTR + t * INTR + j] * bk[j];
        bavs[t] = a;
    }
    __syncthreads();
    if (t < INTR) {
        float a = 0.f;
        #pragma unroll 4
        for (int i = 0; i < INTR; ++i) a += wwg[t * INTR + i] * bavs[i];
        b2s[t] = swg[t] * a + twg[t];
    }
    __syncthreads();
    float a = 0.f;
    #pragma unroll 4
    for (int o = 0; o < INTR; ++o) a += wout[t * INTR + o] * b2s[o];
    float b5 = a + bout[t];
    b6[b * CCH + t] = sout[t] * b5 + tout[t];
}

// ---------- 10. W2 ----------
__global__ __launch_bounds__(256) void w2_kernel(const float* __restrict__ wwg,
                                                 const float* __restrict__ Wav,
                                                 const float* __restrict__ swg,
                                                 float* __restrict__ W2) {
    int bid = blockIdx.x;
    int o = bid & 127, b = bid >> 7;
    int t = threadIdx.x;
    __shared__ float wr[INTR];
    if (t < INTR) wr[t] = wwg[o * INTR + t];
    __syncthreads();
    float acc = 0.f;
    #pragma unroll 4
    for (int i = 0; i < INTR; ++i) acc += wr[i] * Wav[(size_t)b * INTR * CCH + i * CCH + t];
    W2[(size_t)b * INTR * CCH + o * CCH + t] = swg[o] * acc;
}

// ---------- 11. W7 f16 ----------
__global__ __launch_bounds__(256) void w7_kernel(const float* __restrict__ wout,
                                                 const float* __restrict__ W2,
                                                 const float* __restrict__ sout,
                                                 const float* __restrict__ scale,
                                                 unsigned short* __restrict__ W7h) {
    int bid = blockIdx.x;
    int c = bid & 255, b = bid >> 8;
    int t = threadIdx.x;
    __shared__ float wr[INTR];
    if (t < INTR) wr[t] = wout[c * INTR + t];
    __syncthreads();
    float acc = 0.f;
    #pragma unroll 4
    for (int o = 0; o < INTR; ++o) acc += wr[o] * W2[(size_t)b * INTR * CCH + o * CCH + t];
    float w6 = sout[c] * acc + ((c == t) ? 1.f : 0.f);
    W7h[(size_t)b * CCH * CCH + c * CCH + t] = h1(w6 * scale[b * CCH + t]);
}

// ---------- 12. out = leaky(W7 @ x + b6) via MFMA f16 ----------
__global__ __launch_bounds__(256, 4) void final_mfma_kernel(const unsigned short* __restrict__ W7h,
                                                            const float* __restrict__ x,
                                                            const float* __restrict__ b6,
                                                            float* __restrict__ out) {
    __shared__ __align__(16) unsigned short Ws[128 * 64];
    __shared__ __align__(16) unsigned short Xs[128 * 64];
    int bid = blockIdx.x;
    int ct = bid & 1;
    int nt = (bid >> 1) & 127;
    int b = bid >> 8;
    int cbase = ct * 128, n0 = nt * 128;
    const float* xb = x + (size_t)b * CCH * NPIX;
    const unsigned short* Wb = W7h + (size_t)b * CCH * CCH;
    int tid = threadIdx.x;
    int l = tid & 63, w = tid >> 6;
    int wrow = (w >> 1) * 64, wcol = (w & 1) * 64;
    int mn = tid & 31, mk0 = tid >> 5;

    f32x16 acc[2][2];
    #pragma unroll
    for (int i = 0; i < 2; ++i)
        #pragma unroll
        for (int j = 0; j < 2; ++j)
            #pragma unroll
            for (int r = 0; r < 16; ++r) acc[i][j][r] = 0.f;

    for (int step = 0; step < 4; ++step) {
        int k0 = step * 64;
        __syncthreads();
        #pragma unroll
        for (int e = 0; e < 4; ++e) {
            int slot = tid + 256 * e;
            int r = slot >> 3, sg = slot & 7;
            uint4 v = *(const uint4*)&Wb[(size_t)(cbase + r) * CCH + k0 + sg * 8];
            *(uint4*)&Ws[r * 64 + ((sg ^ (r & 7)) << 3)] = v;
        }
        #pragma unroll
        for (int mi = 0; mi < 2; ++mi) {
            int mk = mk0 + mi * 8;
            const float* sp = &xb[(size_t)(k0 + mk * 4) * NPIX + n0 + mn * 4];
            float4 q0 = *(const float4*)sp;
            float4 q1 = *(const float4*)(sp + NPIX);
            float4 q2 = *(const float4*)(sp + 2 * NPIX);
            float4 q3 = *(const float4*)(sp + 3 * NPIX);
            int klo = mk * 4;
            int unit = klo >> 3, sub = (klo & 7) >> 2;
            #pragma unroll
            for (int j = 0; j < 4; ++j) {
                float e0 = j == 0 ? q0.x : j == 1 ? q0.y : j == 2 ? q0.z : q0.w;
                float e1 = j == 0 ? q1.x : j == 1 ? q1.y : j == 2 ? q1.z : q1.w;
                float e2 = j == 0 ? q2.x : j == 1 ? q2.y : j == 2 ? q2.z : q2.w;
                float e3 = j == 0 ? q3.x : j == 1 ? q3.y : j == 2 ? q3.z : q3.w;
                int nl = mn * 4 + j;
                ushort4 cv = make_ushort4(h1(e0), h1(e1), h1(e2), h1(e3));
                int idx = nl * 64 + ((unit ^ ((nl >> 2) & 7)) << 3) + sub * 4;
                *(ushort4*)&Xs[idx] = cv;
            }
        }
        __syncthreads();
        #pragma unroll
        for (int kk = 0; kk < 4; ++kk) {
            int useg = kk * 2 + (l >> 5);
            f16x8 af[2], bfr[2];
            #pragma unroll
            for (int at = 0; at < 2; ++at) {
                int c = wrow + at * 32 + (l & 31);
                af[at] = *(const f16x8*)&Ws[c * 64 + ((useg ^ (c & 7)) << 3)];
            }
            #pragma unroll
            for (int bt = 0; bt < 2; ++bt) {
                int n = wcol + bt * 32 + (l & 31);
                bfr[bt] = *(const f16x8*)&Xs[n * 64 + ((useg ^ ((n >> 2) & 7)) << 3)];
            }
            #pragma unroll
            for (int at = 0; at < 2; ++at)
                #pragma unroll
                for (int bt = 0; bt < 2; ++bt)
                    acc[at][bt] = __builtin_amdgcn_mfma_f32_32x32x16_f16(af[at], bfr[bt], acc[at][bt], 0, 0, 0);
        }
    }
    #pragma unroll
    for (int at = 0; at < 2; ++at)
        #pragma unroll
        for (int bt = 0; bt < 2; ++bt)
            #pragma unroll
            for (int r = 0; r < 16; ++r) {
                int c = cbase + wrow + at * 32 + (r & 3) + ((r >> 2) << 3) + ((l >> 5) << 2);
                int n = n0 + wcol + bt * 32 + (l & 31);
                float v = acc[at][bt][r] + b6[b * CCH + c];
                v = v > 0.f ? v : SLOPE * v;
                out[(size_t)b * CCH * NPIX + (size_t)c * NPIX + n] = v;
            }
}

extern "C" void kernel_launch(void* const* d_in, const int* in_sizes, int n_in,
                              void* d_out, int out_size, void* d_ws, size_t ws_size,
                              hipStream_t stream) {
    (void)in_sizes; (void)n_in; (void)out_size;
    const float* x      = (const float*)d_in[0];
    const float* se_w1  = (const float*)d_in[1];
    const float* se_w2  = (const float*)d_in[2];
    const float* wq     = (const float*)d_in[3];
    const float* bq     = (const float*)d_in[4];
    const float* wk     = (const float*)d_in[5];
    const float* bk     = (const float*)d_in[6];
    const float* wv     = (const float*)d_in[7];
    const float* bv     = (const float*)d_in[8];
    const float* w_wg   = (const float*)d_in[9];
    const float* w_out  = (const float*)d_in[14];
    const float* b_out  = (const float*)d_in[15];
    float* out = (float*)d_out;
    float* ws = (float*)d_ws;

    // pick split-K chunk count (power of 2) that fits the workspace
    size_t avail = ws_size / sizeof(float);
    int nch = 32;
    while (nch > 1 && (size_t)OFF_PART + (size_t)NB * 3 * nch * 16384 > avail) nch >>= 1;

    hipMemsetAsync(ws + OFF_YM, 0, (size_t)NB * CCH * sizeof(float), stream);
    gram_partial_kernel<<<NB * 3 * nch, 256, 0, stream>>>(x, ws + OFF_PART, ws + OFF_YM, nch);
    gram_reduce_kernel<<<NB * 3 * 16, 256, 0, stream>>>(ws + OFF_PART, ws + OFF_GX, nch);
    se_kernel<<<NB, 256, 0, stream>>>(ws + OFF_YM, se_w1, se_w2, ws + OFF_SC, ws + OFF_RS);
    prep_kernel<<<1, 256, 0, stream>>>((const float*)d_in[10], (const float*)d_in[11],
                                       (const float*)d_in[12], (const float*)d_in[13],
                                       (const float*)d_in[16], (const float*)d_in[17],
                                       (const float*)d_in[18], (const float*)d_in[19],
                                       ws + OFF_SWG, ws + OFF_TWG, ws + OFF_SOUT, ws + OFF_TOUT);
    qsvs_kernel<<<NB, 256, 0, stream>>>(wq, wv, ws + OFF_RS, ws + OFF_QS, ws + OFF_VS);
    ts_kernel<<<NB * INTR, 256, 0, stream>>>(wq, ws + OFF_SC, ws + OFF_GX, wv, bq, bv,
                                             ws + OFF_QS, ws + OFF_VS, ws + OFF_M);
    wav_kernel<<<NB * INTR, 256, 0, stream>>>(ws + OFF_M, wk, ws + OFF_WAV);
    biaschain_kernel<<<NB, 256, 0, stream>>>(ws + OFF_M, bk, w_wg, ws + OFF_SWG, ws + OFF_TWG,
                                             w_out, b_out, ws + OFF_SOUT, ws + OFF_TOUT, ws + OFF_B6);
    w2_kernel<<<NB * INTR, 256, 0, stream>>>(w_wg, ws + OFF_WAV, ws + OFF_SWG, ws + OFF_W2);
    w7_kernel<<<NB * CCH, 256, 0, stream>>>(w_out, ws + OFF_W2, ws + OFF_SOUT, ws + OFF_SC,
                                            (unsigned short*)(ws + OFF_W7));
    final_mfma_kernel<<<NB * 2 * 128, 256, 0, stream>>>((const unsigned short*)(ws + OFF_W7),
                                                        x, ws + OFF_B6, out);
}